// Round 1
// baseline (3434.854 us; speedup 1.0000x reference)
//
#include <hip/hip_runtime.h>
#include <hip/hip_bf16.h>

constexpr int N_NODES   = 500000;
constexpr int N_EDGES   = 8000000;
constexpr int NUM_GRAPHS = 512;

// ---------------- degree ----------------
__global__ void k_deg(const int* __restrict__ dst, float* __restrict__ deg) {
  int i = blockIdx.x * blockDim.x + threadIdx.x;
  if (i < N_EDGES) atomicAdd(&deg[dst[i]], 1.0f);
}

__global__ void k_dinv(float* __restrict__ deg) {
  int i = blockIdx.x * blockDim.x + threadIdx.x;
  if (i < N_NODES) deg[i] = rsqrtf(deg[i] + 1.0f);   // in-degree + self loop
}

// ---------------- layer 1 scatter: agg1[dst] += norm * (x[src] @ W1) ----------------
// 16 lanes per edge, one feature each. h computed on the fly (x is 3-wide).
__global__ void k_scatter1(const int* __restrict__ src, const int* __restrict__ dst,
                           const float* __restrict__ x, const float* __restrict__ W1,
                           const float* __restrict__ dinv, float* __restrict__ agg1) {
  unsigned t = blockIdx.x * blockDim.x + threadIdx.x;
  unsigned e = t >> 4;
  int f = t & 15;
  if (e >= (unsigned)N_EDGES) return;
  int s = src[e], d = dst[e];
  float nrm = dinv[s] * dinv[d];
  const float* xs = x + (size_t)s * 3;
  float h = xs[0] * W1[f] + xs[1] * W1[16 + f] + xs[2] * W1[32 + f];
  atomicAdd(&agg1[(size_t)d * 16 + f], nrm * h);
}

// ---------------- layer 1 finalize: out1 = relu(agg1 + dinv^2 * h + b1) ----------------
__global__ void k_fin1(const float* __restrict__ x, const float* __restrict__ W1,
                       const float* __restrict__ b1, const float* __restrict__ dinv,
                       const float* __restrict__ agg1, float* __restrict__ out1) {
  unsigned t = blockIdx.x * blockDim.x + threadIdx.x;
  unsigned n = t >> 4;
  int f = t & 15;
  if (n >= (unsigned)N_NODES) return;
  float di = dinv[n];
  const float* xs = x + (size_t)n * 3;
  float h = xs[0] * W1[f] + xs[1] * W1[16 + f] + xs[2] * W1[32 + f];
  float v = agg1[(size_t)n * 16 + f] + di * di * h + b1[f];
  out1[(size_t)n * 16 + f] = fmaxf(v, 0.0f);
}

// ---------------- layer 2 scatter: agg2[dst] += norm * (out1[src] @ W2) ----------------
// 32 lanes per edge, one output feature each; W2 (16x32) staged in LDS.
__global__ void k_scatter2(const int* __restrict__ src, const int* __restrict__ dst,
                           const float* __restrict__ out1, const float* __restrict__ W2,
                           const float* __restrict__ dinv, float* __restrict__ agg2) {
  __shared__ float w2s[16 * 32];
  for (int i = threadIdx.x; i < 16 * 32; i += blockDim.x) w2s[i] = W2[i];
  __syncthreads();
  unsigned t = blockIdx.x * blockDim.x + threadIdx.x;
  unsigned e = t >> 5;
  int f = t & 31;
  if (e >= (unsigned)N_EDGES) return;
  int s = src[e], d = dst[e];
  float nrm = dinv[s] * dinv[d];
  const float* o = out1 + (size_t)s * 16;
  float acc = 0.0f;
#pragma unroll
  for (int k = 0; k < 16; ++k) acc += o[k] * w2s[k * 32 + f];
  atomicAdd(&agg2[(size_t)d * 32 + f], nrm * acc);
}

// ---------------- layer 2 finalize + mean-pool accumulation ----------------
__global__ void k_fin2_pool(const float* __restrict__ out1, const float* __restrict__ W2,
                            const float* __restrict__ b2, const float* __restrict__ dinv,
                            const float* __restrict__ agg2, const int* __restrict__ batch,
                            float* __restrict__ sums, float* __restrict__ cnt) {
  __shared__ float w2s[16 * 32];
  for (int i = threadIdx.x; i < 16 * 32; i += blockDim.x) w2s[i] = W2[i];
  __syncthreads();
  unsigned t = blockIdx.x * blockDim.x + threadIdx.x;
  unsigned n = t >> 5;
  int f = t & 31;
  if (n >= (unsigned)N_NODES) return;
  float di = dinv[n];
  const float* o = out1 + (size_t)n * 16;
  float h = 0.0f;
#pragma unroll
  for (int k = 0; k < 16; ++k) h += o[k] * w2s[k * 32 + f];
  float v = fmaxf(agg2[(size_t)n * 32 + f] + di * di * h + b2[f], 0.0f);
  int g = batch[n];
  atomicAdd(&sums[(size_t)g * 32 + f], v);
  if (f == 0) atomicAdd(&cnt[g], 1.0f);
}

// ---------------- final MLP + log_softmax: one thread per graph ----------------
__global__ void k_mlp(const float* __restrict__ sums, const float* __restrict__ cnt,
                      const float* __restrict__ fW1, const float* __restrict__ fb1,
                      const float* __restrict__ fW2, const float* __restrict__ fb2,
                      float* __restrict__ out) {
  __shared__ float w1s[32 * 64];
  __shared__ float w2s[64 * 3];
  __shared__ float b1s[64];
  __shared__ float b2s[3];
  for (int i = threadIdx.x; i < 32 * 64; i += blockDim.x) w1s[i] = fW1[i];
  for (int i = threadIdx.x; i < 64 * 3; i += blockDim.x) w2s[i] = fW2[i];
  for (int i = threadIdx.x; i < 64; i += blockDim.x) b1s[i] = fb1[i];
  for (int i = threadIdx.x; i < 3; i += blockDim.x) b2s[i] = fb2[i];
  __syncthreads();
  int g = blockIdx.x * blockDim.x + threadIdx.x;
  if (g >= NUM_GRAPHS) return;
  float c = fmaxf(cnt[g], 1.0f);
  float p[32];
#pragma unroll
  for (int i = 0; i < 32; ++i) p[i] = sums[(size_t)g * 32 + i] / c;
  float z2[3] = {b2s[0], b2s[1], b2s[2]};
  for (int j = 0; j < 64; ++j) {
    float a = b1s[j];
#pragma unroll
    for (int i = 0; i < 32; ++i) a += p[i] * w1s[i * 64 + j];
    a = fmaxf(a, 0.0f);
#pragma unroll
    for (int k = 0; k < 3; ++k) z2[k] += a * w2s[j * 3 + k];
  }
  float m = fmaxf(fmaxf(z2[0], z2[1]), z2[2]);
  float l = logf(expf(z2[0] - m) + expf(z2[1] - m) + expf(z2[2] - m));
#pragma unroll
  for (int k = 0; k < 3; ++k) out[(size_t)g * 3 + k] = z2[k] - m - l;
}

extern "C" void kernel_launch(void* const* d_in, const int* in_sizes, int n_in,
                              void* d_out, int out_size, void* d_ws, size_t ws_size,
                              hipStream_t stream) {
  const float* x     = (const float*)d_in[0];
  const int*   ei    = (const int*)d_in[1];   // [2, E] int
  const int*   batch = (const int*)d_in[2];
  const float* W1    = (const float*)d_in[3];
  const float* b1    = (const float*)d_in[4];
  const float* W2    = (const float*)d_in[5];
  const float* b2    = (const float*)d_in[6];
  const float* fW1   = (const float*)d_in[7];
  const float* fb1   = (const float*)d_in[8];
  const float* fW2   = (const float*)d_in[9];
  const float* fb2   = (const float*)d_in[10];
  const int* src = ei;
  const int* dst = ei + N_EDGES;

  // workspace layout (float offsets)
  float* ws = (float*)d_ws;
  float* deg  = ws;                         // 500000   (becomes dinv in place)
  float* agg1 = ws + 524288;                // 8M floats  (32 MB)
  float* out1 = ws + 524288 + 8000000;      // 8M floats  (32 MB)
  float* agg2 = ws + 524288 + 16000000;     // 16M floats (64 MB)
  float* sums = ws + 524288 + 32000000;     // 512*32
  float* cnt  = sums + NUM_GRAPHS * 32;     // 512

  // zero deg+agg1 (contiguous) and agg2+sums+cnt (contiguous); skip out1
  hipMemsetAsync(deg, 0, (size_t)(524288 + 8000000) * 4, stream);
  hipMemsetAsync(agg2, 0, (size_t)(16000000 + NUM_GRAPHS * 32 + NUM_GRAPHS) * 4, stream);

  const int B = 256;
  k_deg<<<(N_EDGES + B - 1) / B, B, 0, stream>>>(dst, deg);
  k_dinv<<<(N_NODES + B - 1) / B, B, 0, stream>>>(deg);
  k_scatter1<<<((size_t)N_EDGES * 16 + B - 1) / B, B, 0, stream>>>(src, dst, x, W1, deg, agg1);
  k_fin1<<<((size_t)N_NODES * 16 + B - 1) / B, B, 0, stream>>>(x, W1, b1, deg, agg1, out1);
  k_scatter2<<<((size_t)N_EDGES * 32 + B - 1) / B, B, 0, stream>>>(src, dst, out1, W2, deg, agg2);
  k_fin2_pool<<<((size_t)N_NODES * 32 + B - 1) / B, B, 0, stream>>>(out1, W2, b2, deg, agg2, batch, sums, cnt);
  k_mlp<<<(NUM_GRAPHS + B - 1) / B, B, 0, stream>>>(sums, cnt, fW1, fb1, fW2, fb2, (float*)d_out);
}

// Round 2
// 2093.442 us; speedup vs baseline: 1.6408x; 1.6408x over previous
//
#include <hip/hip_runtime.h>
#include <hip/hip_bf16.h>

constexpr int N_NODES    = 500000;
constexpr int N_EDGES    = 8000000;
constexpr int NUM_GRAPHS = 512;

// ---------------- degree ----------------
__global__ void k_deg(const int* __restrict__ dst, float* __restrict__ deg) {
  int i = blockIdx.x * blockDim.x + threadIdx.x;
  if (i < N_EDGES) atomicAdd(&deg[dst[i]], 1.0f);
}

__global__ void k_dinv(float* __restrict__ deg) {
  int i = blockIdx.x * blockDim.x + threadIdx.x;
  if (i < N_NODES) deg[i] = rsqrtf(deg[i] + 1.0f);   // in-degree + self loop
}

// ---------------- graph segment boundaries: start[g] = lower_bound(batch, g) ----------------
__global__ void k_bounds(const int* __restrict__ batch, int* __restrict__ start) {
  int g = blockIdx.x * blockDim.x + threadIdx.x;
  if (g > NUM_GRAPHS) return;
  int lo = 0, hi = N_NODES;
  while (lo < hi) { int mid = (lo + hi) >> 1; if (batch[mid] < g) lo = mid + 1; else hi = mid; }
  start[g] = lo;
}

// ---------------- layer 1 scatter (pre-matmul): aggx[dst] += norm * x[src]  (3 floats/edge) ----
__global__ void k_scatter1(const int* __restrict__ src, const int* __restrict__ dst,
                           const float* __restrict__ x, const float* __restrict__ dinv,
                           float* __restrict__ aggx) {
  unsigned e = blockIdx.x * blockDim.x + threadIdx.x;
  if (e >= (unsigned)N_EDGES) return;
  int s = src[e], d = dst[e];
  float nrm = dinv[s] * dinv[d];
  const float* xs = x + (size_t)s * 3;
  float* ad = aggx + (size_t)d * 3;
  atomicAdd(&ad[0], nrm * xs[0]);
  atomicAdd(&ad[1], nrm * xs[1]);
  atomicAdd(&ad[2], nrm * xs[2]);
}

// ---------------- layer 1 finalize: out1 = relu((aggx + dinv^2*x) @ W1 + b1) ----------------
__global__ void k_fin1(const float* __restrict__ x, const float* __restrict__ W1,
                       const float* __restrict__ b1, const float* __restrict__ dinv,
                       const float* __restrict__ aggx, float* __restrict__ out1) {
  unsigned t = blockIdx.x * blockDim.x + threadIdx.x;
  unsigned n = t >> 4;
  int f = t & 15;
  if (n >= (unsigned)N_NODES) return;
  float di = dinv[n], di2 = di * di;
  const float* xs = x + (size_t)n * 3;
  const float* ax = aggx + (size_t)n * 3;
  float t0 = ax[0] + di2 * xs[0];
  float t1 = ax[1] + di2 * xs[1];
  float t2 = ax[2] + di2 * xs[2];
  float v = t0 * W1[f] + t1 * W1[16 + f] + t2 * W1[32 + f] + b1[f];
  out1[(size_t)n * 16 + f] = fmaxf(v, 0.0f);
}

// ---------------- layer 2 scatter (pre-matmul): aggo[dst] += norm * out1[src] (16 f/edge) ----
__global__ void k_scatter2(const int* __restrict__ src, const int* __restrict__ dst,
                           const float* __restrict__ out1, const float* __restrict__ dinv,
                           float* __restrict__ aggo) {
  unsigned t = blockIdx.x * blockDim.x + threadIdx.x;
  unsigned e = t >> 4;
  int f = t & 15;
  if (e >= (unsigned)N_EDGES) return;
  int s = src[e], d = dst[e];
  float nrm = dinv[s] * dinv[d];
  atomicAdd(&aggo[(size_t)d * 16 + f], nrm * out1[(size_t)s * 16 + f]);
}

// ---------------- pool: one block per graph, atomic-free ----------------
// v[n,f] = relu(((aggo[n] + dinv^2*out1[n]) @ W2)[f] + b2[f]); sums[g,f] = sum over segment
__global__ void k_pool(const float* __restrict__ out1, const float* __restrict__ aggo,
                       const float* __restrict__ W2, const float* __restrict__ b2,
                       const float* __restrict__ dinv, const int* __restrict__ start,
                       float* __restrict__ sums, float* __restrict__ cnt) {
  __shared__ float w2s[16 * 32];
  __shared__ float red[8][32];
  for (int i = threadIdx.x; i < 16 * 32; i += blockDim.x) w2s[i] = W2[i];
  __syncthreads();
  int g = blockIdx.x;
  int s0 = start[g], s1 = start[g + 1];
  int f = threadIdx.x & 31, sub = threadIdx.x >> 5;
  float bf = b2[f];
  float acc = 0.0f;
  for (int n = s0 + sub; n < s1; n += 8) {
    float di = dinv[n], di2 = di * di;
    const float* ar = aggo + (size_t)n * 16;
    const float* o  = out1 + (size_t)n * 16;
    float v = bf;
#pragma unroll
    for (int k = 0; k < 16; ++k) v += (ar[k] + di2 * o[k]) * w2s[k * 32 + f];
    acc += fmaxf(v, 0.0f);
  }
  red[sub][f] = acc;
  __syncthreads();
  if (threadIdx.x < 32) {
    float tot = 0.0f;
#pragma unroll
    for (int i = 0; i < 8; ++i) tot += red[i][threadIdx.x];
    sums[(size_t)g * 32 + threadIdx.x] = tot;
  }
  if (threadIdx.x == 0) cnt[g] = (float)(s1 - s0);
}

// ---------------- final MLP + log_softmax: one thread per graph ----------------
__global__ void k_mlp(const float* __restrict__ sums, const float* __restrict__ cnt,
                      const float* __restrict__ fW1, const float* __restrict__ fb1,
                      const float* __restrict__ fW2, const float* __restrict__ fb2,
                      float* __restrict__ out) {
  __shared__ float w1s[32 * 64];
  __shared__ float w2s[64 * 3];
  __shared__ float b1s[64];
  __shared__ float b2s[3];
  for (int i = threadIdx.x; i < 32 * 64; i += blockDim.x) w1s[i] = fW1[i];
  for (int i = threadIdx.x; i < 64 * 3; i += blockDim.x) w2s[i] = fW2[i];
  for (int i = threadIdx.x; i < 64; i += blockDim.x) b1s[i] = fb1[i];
  for (int i = threadIdx.x; i < 3; i += blockDim.x) b2s[i] = fb2[i];
  __syncthreads();
  int g = blockIdx.x * blockDim.x + threadIdx.x;
  if (g >= NUM_GRAPHS) return;
  float c = fmaxf(cnt[g], 1.0f);
  float p[32];
#pragma unroll
  for (int i = 0; i < 32; ++i) p[i] = sums[(size_t)g * 32 + i] / c;
  float z2[3] = {b2s[0], b2s[1], b2s[2]};
  for (int j = 0; j < 64; ++j) {
    float a = b1s[j];
#pragma unroll
    for (int i = 0; i < 32; ++i) a += p[i] * w1s[i * 64 + j];
    a = fmaxf(a, 0.0f);
#pragma unroll
    for (int k = 0; k < 3; ++k) z2[k] += a * w2s[j * 3 + k];
  }
  float m = fmaxf(fmaxf(z2[0], z2[1]), z2[2]);
  float l = logf(expf(z2[0] - m) + expf(z2[1] - m) + expf(z2[2] - m));
#pragma unroll
  for (int k = 0; k < 3; ++k) out[(size_t)g * 3 + k] = z2[k] - m - l;
}

extern "C" void kernel_launch(void* const* d_in, const int* in_sizes, int n_in,
                              void* d_out, int out_size, void* d_ws, size_t ws_size,
                              hipStream_t stream) {
  const float* x     = (const float*)d_in[0];
  const int*   ei    = (const int*)d_in[1];   // [2, E]
  const int*   batch = (const int*)d_in[2];
  const float* W1    = (const float*)d_in[3];
  const float* b1    = (const float*)d_in[4];
  const float* W2    = (const float*)d_in[5];
  const float* b2    = (const float*)d_in[6];
  const float* fW1   = (const float*)d_in[7];
  const float* fb1   = (const float*)d_in[8];
  const float* fW2   = (const float*)d_in[9];
  const float* fb2   = (const float*)d_in[10];
  const int* src = ei;
  const int* dst = ei + N_EDGES;

  // workspace layout (float offsets)
  float* ws   = (float*)d_ws;
  float* deg  = ws;                          // 500000 (becomes dinv in place)
  float* aggx = ws + 524288;                 // 500000*3 = 1.5M floats
  float* out1 = aggx + 1500000;              // 8M floats (32 MB)
  float* aggo = out1 + 8000000;              // 8M floats (32 MB)
  float* sums = aggo + 8000000;              // 512*32
  float* cnt  = sums + NUM_GRAPHS * 32;      // 512
  int*   gstart = (int*)(cnt + NUM_GRAPHS);  // 513 ints

  // zero: deg+aggx contiguous (8.1 MB); aggo (32 MB). sums/cnt written directly.
  hipMemsetAsync(deg, 0, (size_t)(524288 + 1500000) * 4, stream);
  hipMemsetAsync(aggo, 0, (size_t)8000000 * 4, stream);

  const int B = 256;
  k_deg<<<(N_EDGES + B - 1) / B, B, 0, stream>>>(dst, deg);
  k_dinv<<<(N_NODES + B - 1) / B, B, 0, stream>>>(deg);
  k_bounds<<<(NUM_GRAPHS + 1 + B - 1) / B, B, 0, stream>>>(batch, gstart);
  k_scatter1<<<(N_EDGES + B - 1) / B, B, 0, stream>>>(src, dst, x, deg, aggx);
  k_fin1<<<((size_t)N_NODES * 16 + B - 1) / B, B, 0, stream>>>(x, W1, b1, deg, aggx, out1);
  k_scatter2<<<((size_t)N_EDGES * 16 + B - 1) / B, B, 0, stream>>>(src, dst, out1, deg, aggo);
  k_pool<<<NUM_GRAPHS, B, 0, stream>>>(out1, aggo, W2, b2, deg, gstart, sums, cnt);
  k_mlp<<<(NUM_GRAPHS + B - 1) / B, B, 0, stream>>>(sums, cnt, fW1, fb1, fW2, fb2, (float*)d_out);
}

// Round 3
// 1307.520 us; speedup vs baseline: 2.6270x; 1.6011x over previous
//
#include <hip/hip_runtime.h>
#include <hip/hip_bf16.h>

constexpr int N_NODES    = 500000;
constexpr int N_EDGES    = 8000000;
constexpr int NUM_GRAPHS = 512;

// ---------------- degree ----------------
__global__ void k_deg(const int* __restrict__ dst, float* __restrict__ deg) {
  int i = blockIdx.x * blockDim.x + threadIdx.x;
  if (i < N_EDGES) atomicAdd(&deg[dst[i]], 1.0f);
}

__global__ void k_dinv(float* __restrict__ deg) {
  int i = blockIdx.x * blockDim.x + threadIdx.x;
  if (i < N_NODES) deg[i] = rsqrtf(deg[i] + 1.0f);   // in-degree + self loop
}

// ---------------- graph segment boundaries: start[g] = lower_bound(batch, g) ----------------
__global__ void k_bounds(const int* __restrict__ batch, int* __restrict__ start) {
  int g = blockIdx.x * blockDim.x + threadIdx.x;
  if (g > NUM_GRAPHS) return;
  int lo = 0, hi = N_NODES;
  while (lo < hi) { int mid = (lo + hi) >> 1; if (batch[mid] < g) lo = mid + 1; else hi = mid; }
  start[g] = lo;
}

// ---------------- layer 1 scatter (pre-matmul): aggx4[dst*4+j] += norm * x[src*3+j] ----------
// 4 lanes per edge (j<3 active): one wave instruction covers 16 edges, ~1 line-RMW per edge.
__global__ void k_scatter1(const int* __restrict__ src, const int* __restrict__ dst,
                           const float* __restrict__ x, const float* __restrict__ dinv,
                           float* __restrict__ aggx4) {
  unsigned t = blockIdx.x * blockDim.x + threadIdx.x;
  unsigned e = t >> 2;
  int j = t & 3;
  if (e >= (unsigned)N_EDGES) return;
  int s = src[e], d = dst[e];
  float nrm = dinv[s] * dinv[d];
  if (j < 3) atomicAdd(&aggx4[(size_t)d * 4 + j], nrm * x[(size_t)s * 3 + j]);
}

// ---------------- layer 1 finalize: out1 = relu((aggx + dinv^2*x) @ W1 + b1) ----------------
__global__ void k_fin1(const float* __restrict__ x, const float* __restrict__ W1,
                       const float* __restrict__ b1, const float* __restrict__ dinv,
                       const float* __restrict__ aggx4, float* __restrict__ out1) {
  unsigned t = blockIdx.x * blockDim.x + threadIdx.x;
  unsigned n = t >> 4;
  int f = t & 15;
  if (n >= (unsigned)N_NODES) return;
  float di = dinv[n], di2 = di * di;
  const float* xs = x + (size_t)n * 3;
  const float* ax = aggx4 + (size_t)n * 4;
  float t0 = ax[0] + di2 * xs[0];
  float t1 = ax[1] + di2 * xs[1];
  float t2 = ax[2] + di2 * xs[2];
  float v = t0 * W1[f] + t1 * W1[16 + f] + t2 * W1[32 + f] + b1[f];
  out1[(size_t)n * 16 + f] = fmaxf(v, 0.0f);
}

// ---------------- layer 2 scatter (pre-matmul): aggo[dst] += norm * out1[src] (16 f/edge) ----
__global__ void k_scatter2(const int* __restrict__ src, const int* __restrict__ dst,
                           const float* __restrict__ out1, const float* __restrict__ dinv,
                           float* __restrict__ aggo) {
  unsigned t = blockIdx.x * blockDim.x + threadIdx.x;
  unsigned e = t >> 4;
  int f = t & 15;
  if (e >= (unsigned)N_EDGES) return;
  int s = src[e], d = dst[e];
  float nrm = dinv[s] * dinv[d];
  atomicAdd(&aggo[(size_t)d * 16 + f], nrm * out1[(size_t)s * 16 + f]);
}

// ---------------- pool: one block per graph, atomic-free ----------------
__global__ void k_pool(const float* __restrict__ out1, const float* __restrict__ aggo,
                       const float* __restrict__ W2, const float* __restrict__ b2,
                       const float* __restrict__ dinv, const int* __restrict__ start,
                       float* __restrict__ sums, float* __restrict__ cnt) {
  __shared__ float w2s[16 * 32];
  __shared__ float red[8][32];
  for (int i = threadIdx.x; i < 16 * 32; i += blockDim.x) w2s[i] = W2[i];
  __syncthreads();
  int g = blockIdx.x;
  int s0 = start[g], s1 = start[g + 1];
  int f = threadIdx.x & 31, sub = threadIdx.x >> 5;
  float bf = b2[f];
  float acc = 0.0f;
  for (int n = s0 + sub; n < s1; n += 8) {
    float di = dinv[n], di2 = di * di;
    const float* ar = aggo + (size_t)n * 16;
    const float* o  = out1 + (size_t)n * 16;
    float v = bf;
#pragma unroll
    for (int k = 0; k < 16; ++k) v += (ar[k] + di2 * o[k]) * w2s[k * 32 + f];
    acc += fmaxf(v, 0.0f);
  }
  red[sub][f] = acc;
  __syncthreads();
  if (threadIdx.x < 32) {
    float tot = 0.0f;
#pragma unroll
    for (int i = 0; i < 8; ++i) tot += red[i][threadIdx.x];
    sums[(size_t)g * 32 + threadIdx.x] = tot;
  }
  if (threadIdx.x == 0) cnt[g] = (float)(s1 - s0);
}

// ---------------- final MLP + log_softmax: one thread per graph ----------------
__global__ void k_mlp(const float* __restrict__ sums, const float* __restrict__ cnt,
                      const float* __restrict__ fW1, const float* __restrict__ fb1,
                      const float* __restrict__ fW2, const float* __restrict__ fb2,
                      float* __restrict__ out) {
  __shared__ float w1s[32 * 64];
  __shared__ float w2s[64 * 3];
  __shared__ float b1s[64];
  __shared__ float b2s[3];
  for (int i = threadIdx.x; i < 32 * 64; i += blockDim.x) w1s[i] = fW1[i];
  for (int i = threadIdx.x; i < 64 * 3; i += blockDim.x) w2s[i] = fW2[i];
  for (int i = threadIdx.x; i < 64; i += blockDim.x) b1s[i] = fb1[i];
  for (int i = threadIdx.x; i < 3; i += blockDim.x) b2s[i] = fb2[i];
  __syncthreads();
  int g = blockIdx.x * blockDim.x + threadIdx.x;
  if (g >= NUM_GRAPHS) return;
  float c = fmaxf(cnt[g], 1.0f);
  float p[32];
#pragma unroll
  for (int i = 0; i < 32; ++i) p[i] = sums[(size_t)g * 32 + i] / c;
  float z2[3] = {b2s[0], b2s[1], b2s[2]};
  for (int j = 0; j < 64; ++j) {
    float a = b1s[j];
#pragma unroll
    for (int i = 0; i < 32; ++i) a += p[i] * w1s[i * 64 + j];
    a = fmaxf(a, 0.0f);
#pragma unroll
    for (int k = 0; k < 3; ++k) z2[k] += a * w2s[j * 3 + k];
  }
  float m = fmaxf(fmaxf(z2[0], z2[1]), z2[2]);
  float l = logf(expf(z2[0] - m) + expf(z2[1] - m) + expf(z2[2] - m));
#pragma unroll
  for (int k = 0; k < 3; ++k) out[(size_t)g * 3 + k] = z2[k] - m - l;
}

extern "C" void kernel_launch(void* const* d_in, const int* in_sizes, int n_in,
                              void* d_out, int out_size, void* d_ws, size_t ws_size,
                              hipStream_t stream) {
  const float* x     = (const float*)d_in[0];
  const int*   ei    = (const int*)d_in[1];   // [2, E]
  const int*   batch = (const int*)d_in[2];
  const float* W1    = (const float*)d_in[3];
  const float* b1    = (const float*)d_in[4];
  const float* W2    = (const float*)d_in[5];
  const float* b2    = (const float*)d_in[6];
  const float* fW1   = (const float*)d_in[7];
  const float* fb1   = (const float*)d_in[8];
  const float* fW2   = (const float*)d_in[9];
  const float* fb2   = (const float*)d_in[10];
  const int* src = ei;
  const int* dst = ei + N_EDGES;

  // workspace layout (float offsets)
  float* ws    = (float*)d_ws;
  float* deg   = ws;                          // 500000 (becomes dinv in place)
  float* aggx4 = ws + 524288;                 // 500000*4 = 2M floats (8 MB, 16B-aligned rows)
  float* out1  = aggx4 + 2000000;             // 8M floats (32 MB)
  float* aggo  = out1 + 8000000;              // 8M floats (32 MB)
  float* sums  = aggo + 8000000;              // 512*32
  float* cnt   = sums + NUM_GRAPHS * 32;      // 512
  int*   gstart = (int*)(cnt + NUM_GRAPHS);   // 513 ints

  // zero: deg+aggx4 contiguous (10 MB); aggo (32 MB). sums/cnt written directly.
  hipMemsetAsync(deg, 0, (size_t)(524288 + 2000000) * 4, stream);
  hipMemsetAsync(aggo, 0, (size_t)8000000 * 4, stream);

  const int B = 256;
  k_deg<<<(N_EDGES + B - 1) / B, B, 0, stream>>>(dst, deg);
  k_dinv<<<(N_NODES + B - 1) / B, B, 0, stream>>>(deg);
  k_bounds<<<(NUM_GRAPHS + 1 + B - 1) / B, B, 0, stream>>>(batch, gstart);
  k_scatter1<<<((size_t)N_EDGES * 4 + B - 1) / B, B, 0, stream>>>(src, dst, x, deg, aggx4);
  k_fin1<<<((size_t)N_NODES * 16 + B - 1) / B, B, 0, stream>>>(x, W1, b1, deg, aggx4, out1);
  k_scatter2<<<((size_t)N_EDGES * 16 + B - 1) / B, B, 0, stream>>>(src, dst, out1, deg, aggo);
  k_pool<<<NUM_GRAPHS, B, 0, stream>>>(out1, aggo, W2, b2, deg, gstart, sums, cnt);
  k_mlp<<<(NUM_GRAPHS + B - 1) / B, B, 0, stream>>>(sums, cnt, fW1, fb1, fW2, fb2, (float*)d_out);
}

// Round 4
// 976.940 us; speedup vs baseline: 3.5159x; 1.3384x over previous
//
#include <hip/hip_runtime.h>
#include <hip/hip_bf16.h>

constexpr int N_NODES    = 500000;
constexpr int N_EDGES    = 8000000;
constexpr int NUM_GRAPHS = 512;
constexpr int SCAN_B     = 256;
constexpr int NB1        = (N_NODES + SCAN_B - 1) / SCAN_B;   // 1954

// ---- count in-degree and per-edge rank within its dst bucket (the ONE atomic pass) ----
__global__ void k_countrank(const int* __restrict__ dst, int* __restrict__ cnt,
                            int* __restrict__ rank) {
  int e = blockIdx.x * blockDim.x + threadIdx.x;
  if (e < N_EDGES) rank[e] = atomicAdd(&cnt[dst[e]], 1);
}

// ---- exclusive scan of cnt -> offs (3 kernels) ----
__global__ void k_scan1(const int* __restrict__ cnt, int* __restrict__ offs,
                        int* __restrict__ bsum) {
  __shared__ int tmp[SCAN_B];
  int t = threadIdx.x;
  int i = blockIdx.x * SCAN_B + t;
  int v = (i < N_NODES) ? cnt[i] : 0;
  tmp[t] = v;
  __syncthreads();
  for (int off = 1; off < SCAN_B; off <<= 1) {
    int a = (t >= off) ? tmp[t - off] : 0;
    __syncthreads();
    tmp[t] += a;
    __syncthreads();
  }
  if (i < N_NODES) offs[i] = tmp[t] - v;
  if (t == SCAN_B - 1) bsum[blockIdx.x] = tmp[t];
}

__global__ void k_scan2(const int* __restrict__ bsum, int* __restrict__ bofs) {
  __shared__ int tmp[SCAN_B];
  int t = threadIdx.x;
  int carry = 0;
  for (int base = 0; base < NB1; base += SCAN_B) {
    int i = base + t;
    int v = (i < NB1) ? bsum[i] : 0;
    tmp[t] = v;
    __syncthreads();
    for (int off = 1; off < SCAN_B; off <<= 1) {
      int a = (t >= off) ? tmp[t - off] : 0;
      __syncthreads();
      tmp[t] += a;
      __syncthreads();
    }
    if (i < NB1) bofs[i] = carry + tmp[t] - v;
    carry += tmp[SCAN_B - 1];
    __syncthreads();
  }
}

__global__ void k_scan3(int* __restrict__ offs, const int* __restrict__ bofs) {
  int i = blockIdx.x * blockDim.x + threadIdx.x;
  if (i < N_NODES) offs[i] += bofs[i >> 8];
  if (i == 0) offs[N_NODES] = N_EDGES;
}

// ---- dinv + pre-scaled padded features xs4[n] = dinv[n]*x[n] (16B rows) ----
__global__ void k_prep(const int* __restrict__ cnt, const float* __restrict__ x,
                       float* __restrict__ dinv, float* __restrict__ xs4) {
  int n = blockIdx.x * blockDim.x + threadIdx.x;
  if (n >= N_NODES) return;
  float di = rsqrtf((float)cnt[n] + 1.0f);
  dinv[n] = di;
  const float* xs = x + (size_t)n * 3;
  float4 v = make_float4(di * xs[0], di * xs[1], di * xs[2], 0.0f);
  *(float4*)(xs4 + (size_t)n * 4) = v;
}

// ---- CSR build: plain random stores, no RMW ----
__global__ void k_build(const int* __restrict__ src, const int* __restrict__ dst,
                        const int* __restrict__ rank, const int* __restrict__ offs,
                        int* __restrict__ ssrc) {
  int e = blockIdx.x * blockDim.x + threadIdx.x;
  if (e >= N_EDGES) return;
  ssrc[offs[dst[e]] + rank[e]] = src[e];
}

// ---- graph segment boundaries ----
__global__ void k_bounds(const int* __restrict__ batch, int* __restrict__ start) {
  int g = blockIdx.x * blockDim.x + threadIdx.x;
  if (g > NUM_GRAPHS) return;
  int lo = 0, hi = N_NODES;
  while (lo < hi) { int mid = (lo + hi) >> 1; if (batch[mid] < g) lo = mid + 1; else hi = mid; }
  start[g] = lo;
}

// ---- layer 1 gather: A1[n] = sum over in-edges of xs4[s] (4 lanes/node) ----
__global__ void k_gather1(const int* __restrict__ ssrc, const int* __restrict__ offs,
                          const float* __restrict__ xs4, float* __restrict__ A1) {
  unsigned t = blockIdx.x * blockDim.x + threadIdx.x;
  unsigned n = t >> 2;
  int j = t & 3;
  if (n >= (unsigned)N_NODES) return;
  int o0 = offs[n], o1 = offs[n + 1];
  float acc = 0.0f;
  for (int i = o0; i < o1; ++i) acc += xs4[(size_t)ssrc[i] * 4 + j];
  A1[(size_t)n * 4 + j] = acc;
}

// ---- layer 1 finalize: u = dinv * relu( (dinv*(A1+xs4)) @ W1 + b1 ) ----
__global__ void k_fin1(const float* __restrict__ A1, const float* __restrict__ xs4,
                       const float* __restrict__ dinv, const float* __restrict__ W1,
                       const float* __restrict__ b1, float* __restrict__ u) {
  unsigned t = blockIdx.x * blockDim.x + threadIdx.x;
  unsigned n = t >> 4;
  int f = t & 15;
  if (n >= (unsigned)N_NODES) return;
  float di = dinv[n];
  const float* a  = A1  + (size_t)n * 4;
  const float* xs = xs4 + (size_t)n * 4;
  float t0 = di * (a[0] + xs[0]);
  float t1 = di * (a[1] + xs[1]);
  float t2 = di * (a[2] + xs[2]);
  float v = t0 * W1[f] + t1 * W1[16 + f] + t2 * W1[32 + f] + b1[f];
  u[(size_t)n * 16 + f] = di * fmaxf(v, 0.0f);
}

// ---- layer 2 gather: A2[n] = sum over in-edges of u[s] (16 lanes/node, 64B line/edge) ----
__global__ void k_gather2(const int* __restrict__ ssrc, const int* __restrict__ offs,
                          const float* __restrict__ u, float* __restrict__ A2) {
  unsigned t = blockIdx.x * blockDim.x + threadIdx.x;
  unsigned n = t >> 4;
  int f = t & 15;
  if (n >= (unsigned)N_NODES) return;
  int o0 = offs[n], o1 = offs[n + 1];
  float acc = 0.0f;
  for (int i = o0; i < o1; ++i) acc += u[(size_t)ssrc[i] * 16 + f];
  A2[(size_t)n * 16 + f] = acc;
}

// ---- pool: h2 = relu( (dinv*(A2+u)) @ W2 + b2 ), segment-sum per graph ----
__global__ void k_pool(const float* __restrict__ u, const float* __restrict__ A2,
                       const float* __restrict__ W2, const float* __restrict__ b2,
                       const float* __restrict__ dinv, const int* __restrict__ start,
                       float* __restrict__ sums, float* __restrict__ cntg) {
  __shared__ float w2s[16 * 32];
  __shared__ float red[8][32];
  for (int i = threadIdx.x; i < 16 * 32; i += blockDim.x) w2s[i] = W2[i];
  __syncthreads();
  int g = blockIdx.x;
  int s0 = start[g], s1 = start[g + 1];
  int f = threadIdx.x & 31, sub = threadIdx.x >> 5;
  float bf = b2[f];
  float acc = 0.0f;
  for (int n = s0 + sub; n < s1; n += 8) {
    float di = dinv[n];
    const float* a2 = A2 + (size_t)n * 16;
    const float* un = u  + (size_t)n * 16;
    float v = bf;
#pragma unroll
    for (int k = 0; k < 16; ++k) v += di * (a2[k] + un[k]) * w2s[k * 32 + f];
    acc += fmaxf(v, 0.0f);
  }
  red[sub][f] = acc;
  __syncthreads();
  if (threadIdx.x < 32) {
    float tot = 0.0f;
#pragma unroll
    for (int i = 0; i < 8; ++i) tot += red[i][threadIdx.x];
    sums[(size_t)g * 32 + threadIdx.x] = tot;
  }
  if (threadIdx.x == 0) cntg[g] = (float)(s1 - s0);
}

// ---- final MLP + log_softmax ----
__global__ void k_mlp(const float* __restrict__ sums, const float* __restrict__ cntg,
                      const float* __restrict__ fW1, const float* __restrict__ fb1,
                      const float* __restrict__ fW2, const float* __restrict__ fb2,
                      float* __restrict__ out) {
  __shared__ float w1s[32 * 64];
  __shared__ float w2s[64 * 3];
  __shared__ float b1s[64];
  __shared__ float b2s[3];
  for (int i = threadIdx.x; i < 32 * 64; i += blockDim.x) w1s[i] = fW1[i];
  for (int i = threadIdx.x; i < 64 * 3; i += blockDim.x) w2s[i] = fW2[i];
  for (int i = threadIdx.x; i < 64; i += blockDim.x) b1s[i] = fb1[i];
  for (int i = threadIdx.x; i < 3; i += blockDim.x) b2s[i] = fb2[i];
  __syncthreads();
  int g = blockIdx.x * blockDim.x + threadIdx.x;
  if (g >= NUM_GRAPHS) return;
  float c = fmaxf(cntg[g], 1.0f);
  float p[32];
#pragma unroll
  for (int i = 0; i < 32; ++i) p[i] = sums[(size_t)g * 32 + i] / c;
  float z2[3] = {b2s[0], b2s[1], b2s[2]};
  for (int j = 0; j < 64; ++j) {
    float a = b1s[j];
#pragma unroll
    for (int i = 0; i < 32; ++i) a += p[i] * w1s[i * 64 + j];
    a = fmaxf(a, 0.0f);
#pragma unroll
    for (int k = 0; k < 3; ++k) z2[k] += a * w2s[j * 3 + k];
  }
  float m = fmaxf(fmaxf(z2[0], z2[1]), z2[2]);
  float l = logf(expf(z2[0] - m) + expf(z2[1] - m) + expf(z2[2] - m));
#pragma unroll
  for (int k = 0; k < 3; ++k) out[(size_t)g * 3 + k] = z2[k] - m - l;
}

extern "C" void kernel_launch(void* const* d_in, const int* in_sizes, int n_in,
                              void* d_out, int out_size, void* d_ws, size_t ws_size,
                              hipStream_t stream) {
  const float* x     = (const float*)d_in[0];
  const int*   ei    = (const int*)d_in[1];   // [2, E]
  const int*   batch = (const int*)d_in[2];
  const float* W1    = (const float*)d_in[3];
  const float* b1    = (const float*)d_in[4];
  const float* W2    = (const float*)d_in[5];
  const float* b2    = (const float*)d_in[6];
  const float* fW1   = (const float*)d_in[7];
  const float* fb1   = (const float*)d_in[8];
  const float* fW2   = (const float*)d_in[9];
  const float* fb2   = (const float*)d_in[10];
  const int* src = ei;
  const int* dst = ei + N_EDGES;

  // ---- workspace layout ----
  float* ws   = (float*)d_ws;
  float* dinv = ws;                         // 524288
  float* xs4  = dinv + 524288;              // 2,000,000 (16B rows)
  float* u    = xs4 + 2000000;              // 8,000,000 (64B rows)
  float* A1   = u + 8000000;                // 2,000,000
  float* sums = A1 + 2000000;               // 16384
  float* cntg = sums + 16384;               // 512
  int* ip     = (int*)(cntg + 512);
  int* cnt    = ip;                         // 524288
  int* offs   = cnt + 524288;               // 524288 (N_NODES+1 used)
  int* bsum   = offs + 524288;              // 2048
  int* bofs   = bsum + 2048;                // 2048
  int* gstart = bofs + 2048;                // 1024 (513 used)
  int* rank   = gstart + 1024;              // 8,000,000
  int* ssrc   = rank + 8000000;             // 8,000,000
  float* A2   = (float*)rank;               // alias: rank dead after k_build

  hipMemsetAsync(cnt, 0, (size_t)524288 * 4, stream);

  const int B = 256;
  k_countrank<<<(N_EDGES + B - 1) / B, B, 0, stream>>>(dst, cnt, rank);
  k_scan1<<<NB1, SCAN_B, 0, stream>>>(cnt, offs, bsum);
  k_scan2<<<1, SCAN_B, 0, stream>>>(bsum, bofs);
  k_scan3<<<(N_NODES + B - 1) / B, B, 0, stream>>>(offs, bofs);
  k_prep<<<(N_NODES + B - 1) / B, B, 0, stream>>>(cnt, x, dinv, xs4);
  k_build<<<(N_EDGES + B - 1) / B, B, 0, stream>>>(src, dst, rank, offs, ssrc);
  k_bounds<<<(NUM_GRAPHS + 1 + B - 1) / B, B, 0, stream>>>(batch, gstart);
  k_gather1<<<((size_t)N_NODES * 4 + B - 1) / B, B, 0, stream>>>(ssrc, offs, xs4, A1);
  k_fin1<<<((size_t)N_NODES * 16 + B - 1) / B, B, 0, stream>>>(A1, xs4, dinv, W1, b1, u);
  k_gather2<<<((size_t)N_NODES * 16 + B - 1) / B, B, 0, stream>>>(ssrc, offs, u, A2);
  k_pool<<<NUM_GRAPHS, B, 0, stream>>>(u, A2, W2, b2, dinv, gstart, sums, cntg);
  k_mlp<<<(NUM_GRAPHS + B - 1) / B, B, 0, stream>>>(sums, cntg, fW1, fb1, fW2, fb2, (float*)d_out);
}

// Round 5
// 666.485 us; speedup vs baseline: 5.1537x; 1.4658x over previous
//
#include <hip/hip_runtime.h>
#include <hip/hip_bf16.h>

constexpr int N_NODES    = 500000;
constexpr int N_EDGES    = 8000000;
constexpr int NUM_GRAPHS = 512;

constexpr int BSHIFT = 12;                              // 4096 nodes / coarse bucket
constexpr int BSIZE  = 1 << BSHIFT;
constexpr int NBKT   = (N_NODES + BSIZE - 1) / BSIZE;   // 123
constexpr int EPB    = 4096;                            // edges per block (pass A)
constexpr int NBLK_A = (N_EDGES + EPB - 1) / EPB;       // 1954
constexpr int NH     = NBKT * NBLK_A;                   // 240342
constexpr int SCAN_B = 256;
constexpr int NSB    = (NH + SCAN_B - 1) / SCAN_B;      // 939

// ---- pass A1: per-block coarse histogram (LDS atomics only) ----
__global__ void k_hist(const int* __restrict__ dst, int* __restrict__ H) {
  __shared__ int h[NBKT];
  for (int i = threadIdx.x; i < NBKT; i += blockDim.x) h[i] = 0;
  __syncthreads();
  int e0 = blockIdx.x * EPB;
  int e1 = min(e0 + EPB, N_EDGES);
  for (int e = e0 + threadIdx.x; e < e1; e += blockDim.x)
    atomicAdd(&h[dst[e] >> BSHIFT], 1);
  __syncthreads();
  for (int i = threadIdx.x; i < NBKT; i += blockDim.x)
    H[i * NBLK_A + blockIdx.x] = h[i];                  // bucket-major
}

// ---- exclusive scan of H (NH ints): 3 kernels ----
__global__ void k_scan1(const int* __restrict__ in, int* __restrict__ out,
                        int* __restrict__ bsum, int n) {
  __shared__ int tmp[SCAN_B];
  int t = threadIdx.x;
  int i = blockIdx.x * SCAN_B + t;
  int v = (i < n) ? in[i] : 0;
  tmp[t] = v;
  __syncthreads();
  for (int off = 1; off < SCAN_B; off <<= 1) {
    int a = (t >= off) ? tmp[t - off] : 0;
    __syncthreads();
    tmp[t] += a;
    __syncthreads();
  }
  if (i < n) out[i] = tmp[t] - v;
  if (t == SCAN_B - 1) bsum[blockIdx.x] = tmp[t];
}

__global__ void k_scan2(int* __restrict__ bsum, int nb) {  // in-place exclusive
  __shared__ int tmp[SCAN_B];
  int t = threadIdx.x;
  int carry = 0;
  for (int base = 0; base < nb; base += SCAN_B) {
    int i = base + t;
    int v = (i < nb) ? bsum[i] : 0;
    tmp[t] = v;
    __syncthreads();
    for (int off = 1; off < SCAN_B; off <<= 1) {
      int a = (t >= off) ? tmp[t - off] : 0;
      __syncthreads();
      tmp[t] += a;
      __syncthreads();
    }
    if (i < nb) bsum[i] = carry + tmp[t] - v;
    carry += tmp[SCAN_B - 1];
    __syncthreads();
  }
}

__global__ void k_scan3(int* __restrict__ out, const int* __restrict__ bsum, int n) {
  int i = blockIdx.x * blockDim.x + threadIdx.x;
  if (i < n) out[i] += bsum[i >> 8];
}

// ---- pass A3: scatter edges into coarse buckets (LDS cursors), packed pairs ----
__global__ void k_scatter_bkt(const int* __restrict__ src, const int* __restrict__ dst,
                              const int* __restrict__ S, int* __restrict__ pairs) {
  __shared__ int cur[NBKT];
  for (int i = threadIdx.x; i < NBKT; i += blockDim.x)
    cur[i] = S[i * NBLK_A + blockIdx.x];
  __syncthreads();
  int e0 = blockIdx.x * EPB;
  int e1 = min(e0 + EPB, N_EDGES);
  for (int e = e0 + threadIdx.x; e < e1; e += blockDim.x) {
    int d = dst[e];
    int pos = atomicAdd(&cur[d >> BSHIFT], 1);
    pairs[pos] = ((d & (BSIZE - 1)) << 19) | src[e];    // src < 2^19
  }
}

// ---- pass B: per-bucket CSR finalize (one block per bucket, 1024 threads) ----
__global__ void __launch_bounds__(1024)
k_csr(const int* __restrict__ pairs, const int* __restrict__ S,
      int* __restrict__ ssrc, int* __restrict__ cnt, int* __restrict__ offs) {
  __shared__ int hist[BSIZE];
  __shared__ int tmp[1024];
  int t = threadIdx.x;
  int bkt = blockIdx.x;
  int n0 = bkt << BSHIFT;
  int e0 = S[bkt * NBLK_A];
  int e1 = (bkt + 1 < NBKT) ? S[(bkt + 1) * NBLK_A] : N_EDGES;
#pragma unroll
  for (int j = 0; j < 4; ++j) hist[t + j * 1024] = 0;
  __syncthreads();
  for (int e = e0 + t; e < e1; e += 1024)
    atomicAdd(&hist[pairs[e] >> 19], 1);
  __syncthreads();
  int c0 = hist[4 * t], c1 = hist[4 * t + 1], c2 = hist[4 * t + 2], c3 = hist[4 * t + 3];
  int tsum = c0 + c1 + c2 + c3;
  tmp[t] = tsum;
  __syncthreads();
  for (int off = 1; off < 1024; off <<= 1) {
    int a = (t >= off) ? tmp[t - off] : 0;
    __syncthreads();
    tmp[t] += a;
    __syncthreads();
  }
  int tbase = tmp[t] - tsum;     // exclusive over threads
  int o0 = tbase, o1 = tbase + c0, o2 = o1 + c1, o3 = o2 + c2;
  hist[4 * t] = o0; hist[4 * t + 1] = o1; hist[4 * t + 2] = o2; hist[4 * t + 3] = o3;
  int oo[4] = {o0, o1, o2, o3};
  int cc[4] = {c0, c1, c2, c3};
#pragma unroll
  for (int j = 0; j < 4; ++j) {
    int n = n0 + 4 * t + j;
    if (n < N_NODES) { cnt[n] = cc[j]; offs[n] = e0 + oo[j]; }
  }
  __syncthreads();
  for (int e = e0 + t; e < e1; e += 1024) {
    int p = pairs[e];
    int r = atomicAdd(&hist[p >> 19], 1);
    ssrc[e0 + r] = p & 0x7FFFF;
  }
  if (bkt == 0 && t == 0) offs[N_NODES] = N_EDGES;
}

// ---- dinv + pre-scaled padded features ----
__global__ void k_prep(const int* __restrict__ cnt, const float* __restrict__ x,
                       float* __restrict__ dinv, float* __restrict__ xs4) {
  int n = blockIdx.x * blockDim.x + threadIdx.x;
  if (n >= N_NODES) return;
  float di = rsqrtf((float)cnt[n] + 1.0f);
  dinv[n] = di;
  const float* xs = x + (size_t)n * 3;
  float4 v = make_float4(di * xs[0], di * xs[1], di * xs[2], 0.0f);
  *(float4*)(xs4 + (size_t)n * 4) = v;
}

// ---- graph segment boundaries ----
__global__ void k_bounds(const int* __restrict__ batch, int* __restrict__ start) {
  int g = blockIdx.x * blockDim.x + threadIdx.x;
  if (g > NUM_GRAPHS) return;
  int lo = 0, hi = N_NODES;
  while (lo < hi) { int mid = (lo + hi) >> 1; if (batch[mid] < g) lo = mid + 1; else hi = mid; }
  start[g] = lo;
}

// ---- layer 1 gather ----
__global__ void k_gather1(const int* __restrict__ ssrc, const int* __restrict__ offs,
                          const float* __restrict__ xs4, float* __restrict__ A1) {
  unsigned t = blockIdx.x * blockDim.x + threadIdx.x;
  unsigned n = t >> 2;
  int j = t & 3;
  if (n >= (unsigned)N_NODES) return;
  int o0 = offs[n], o1 = offs[n + 1];
  float acc = 0.0f;
  for (int i = o0; i < o1; ++i) acc += xs4[(size_t)ssrc[i] * 4 + j];
  A1[(size_t)n * 4 + j] = acc;
}

// ---- layer 1 finalize: u = dinv * relu( (dinv*(A1+xs4)) @ W1 + b1 ) ----
__global__ void k_fin1(const float* __restrict__ A1, const float* __restrict__ xs4,
                       const float* __restrict__ dinv, const float* __restrict__ W1,
                       const float* __restrict__ b1, float* __restrict__ u) {
  unsigned t = blockIdx.x * blockDim.x + threadIdx.x;
  unsigned n = t >> 4;
  int f = t & 15;
  if (n >= (unsigned)N_NODES) return;
  float di = dinv[n];
  const float* a  = A1  + (size_t)n * 4;
  const float* xs = xs4 + (size_t)n * 4;
  float t0 = di * (a[0] + xs[0]);
  float t1 = di * (a[1] + xs[1]);
  float t2 = di * (a[2] + xs[2]);
  float v = t0 * W1[f] + t1 * W1[16 + f] + t2 * W1[32 + f] + b1[f];
  u[(size_t)n * 16 + f] = di * fmaxf(v, 0.0f);
}

// ---- layer 2 gather ----
__global__ void k_gather2(const int* __restrict__ ssrc, const int* __restrict__ offs,
                          const float* __restrict__ u, float* __restrict__ A2) {
  unsigned t = blockIdx.x * blockDim.x + threadIdx.x;
  unsigned n = t >> 4;
  int f = t & 15;
  if (n >= (unsigned)N_NODES) return;
  int o0 = offs[n], o1 = offs[n + 1];
  float acc = 0.0f;
  for (int i = o0; i < o1; ++i) acc += u[(size_t)ssrc[i] * 16 + f];
  A2[(size_t)n * 16 + f] = acc;
}

// ---- pool ----
__global__ void k_pool(const float* __restrict__ u, const float* __restrict__ A2,
                       const float* __restrict__ W2, const float* __restrict__ b2,
                       const float* __restrict__ dinv, const int* __restrict__ start,
                       float* __restrict__ sums, float* __restrict__ cntg) {
  __shared__ float w2s[16 * 32];
  __shared__ float red[8][32];
  for (int i = threadIdx.x; i < 16 * 32; i += blockDim.x) w2s[i] = W2[i];
  __syncthreads();
  int g = blockIdx.x;
  int s0 = start[g], s1 = start[g + 1];
  int f = threadIdx.x & 31, sub = threadIdx.x >> 5;
  float bf = b2[f];
  float acc = 0.0f;
  for (int n = s0 + sub; n < s1; n += 8) {
    float di = dinv[n];
    const float* a2 = A2 + (size_t)n * 16;
    const float* un = u  + (size_t)n * 16;
    float v = bf;
#pragma unroll
    for (int k = 0; k < 16; ++k) v += di * (a2[k] + un[k]) * w2s[k * 32 + f];
    acc += fmaxf(v, 0.0f);
  }
  red[sub][f] = acc;
  __syncthreads();
  if (threadIdx.x < 32) {
    float tot = 0.0f;
#pragma unroll
    for (int i = 0; i < 8; ++i) tot += red[i][threadIdx.x];
    sums[(size_t)g * 32 + threadIdx.x] = tot;
  }
  if (threadIdx.x == 0) cntg[g] = (float)(s1 - s0);
}

// ---- final MLP + log_softmax ----
__global__ void k_mlp(const float* __restrict__ sums, const float* __restrict__ cntg,
                      const float* __restrict__ fW1, const float* __restrict__ fb1,
                      const float* __restrict__ fW2, const float* __restrict__ fb2,
                      float* __restrict__ out) {
  __shared__ float w1s[32 * 64];
  __shared__ float w2s[64 * 3];
  __shared__ float b1s[64];
  __shared__ float b2s[3];
  for (int i = threadIdx.x; i < 32 * 64; i += blockDim.x) w1s[i] = fW1[i];
  for (int i = threadIdx.x; i < 64 * 3; i += blockDim.x) w2s[i] = fW2[i];
  for (int i = threadIdx.x; i < 64; i += blockDim.x) b1s[i] = fb1[i];
  for (int i = threadIdx.x; i < 3; i += blockDim.x) b2s[i] = fb2[i];
  __syncthreads();
  int g = blockIdx.x * blockDim.x + threadIdx.x;
  if (g >= NUM_GRAPHS) return;
  float c = fmaxf(cntg[g], 1.0f);
  float p[32];
#pragma unroll
  for (int i = 0; i < 32; ++i) p[i] = sums[(size_t)g * 32 + i] / c;
  float z2[3] = {b2s[0], b2s[1], b2s[2]};
  for (int j = 0; j < 64; ++j) {
    float a = b1s[j];
#pragma unroll
    for (int i = 0; i < 32; ++i) a += p[i] * w1s[i * 64 + j];
    a = fmaxf(a, 0.0f);
#pragma unroll
    for (int k = 0; k < 3; ++k) z2[k] += a * w2s[j * 3 + k];
  }
  float m = fmaxf(fmaxf(z2[0], z2[1]), z2[2]);
  float l = logf(expf(z2[0] - m) + expf(z2[1] - m) + expf(z2[2] - m));
#pragma unroll
  for (int k = 0; k < 3; ++k) out[(size_t)g * 3 + k] = z2[k] - m - l;
}

extern "C" void kernel_launch(void* const* d_in, const int* in_sizes, int n_in,
                              void* d_out, int out_size, void* d_ws, size_t ws_size,
                              hipStream_t stream) {
  const float* x     = (const float*)d_in[0];
  const int*   ei    = (const int*)d_in[1];   // [2, E]
  const int*   batch = (const int*)d_in[2];
  const float* W1    = (const float*)d_in[3];
  const float* b1    = (const float*)d_in[4];
  const float* W2    = (const float*)d_in[5];
  const float* b2    = (const float*)d_in[6];
  const float* fW1   = (const float*)d_in[7];
  const float* fb1   = (const float*)d_in[8];
  const float* fW2   = (const float*)d_in[9];
  const float* fb2   = (const float*)d_in[10];
  const int* src = ei;
  const int* dst = ei + N_EDGES;

  // ---- workspace layout (≈118 MB, no memsets needed) ----
  float* ws   = (float*)d_ws;
  float* dinv = ws;                          // 524288
  float* xs4  = dinv + 524288;               // 2,000,000
  float* u    = xs4 + 2000000;               // 8,000,000
  float* A1   = u + 8000000;                 // 2,000,000 (scan scratch aliased inside)
  float* sums = A1 + 2000000;                // 16384
  float* cntg = sums + 16384;                // 512
  int* ip     = (int*)(cntg + 512);
  int* cnt    = ip;                          // 524288
  int* offs   = cnt + 524288;                // 524288 (N_NODES+1 used)
  int* gstart = offs + 524288;               // 1024 (513 used)
  int* ssrc   = gstart + 1024;               // 8,000,000
  int* pairs  = ssrc + 8000000;              // 8,000,000
  // aliases (dead ranges reused):
  int* H    = (int*)A1;                      // 262144 (NH=240342 used)
  int* Sarr = H + 262144;                    // 262144
  int* bsum = Sarr + 262144;                 // 1024 (NSB=939 used)
  float* A2 = (float*)pairs;                 // pairs dead after k_csr

  const int B = 256;
  k_hist<<<NBLK_A, B, 0, stream>>>(dst, H);
  k_scan1<<<NSB, SCAN_B, 0, stream>>>(H, Sarr, bsum, NH);
  k_scan2<<<1, SCAN_B, 0, stream>>>(bsum, NSB);
  k_scan3<<<(NH + B - 1) / B, B, 0, stream>>>(Sarr, bsum, NH);
  k_scatter_bkt<<<NBLK_A, B, 0, stream>>>(src, dst, Sarr, pairs);
  k_csr<<<NBKT, 1024, 0, stream>>>(pairs, Sarr, ssrc, cnt, offs);
  k_prep<<<(N_NODES + B - 1) / B, B, 0, stream>>>(cnt, x, dinv, xs4);
  k_bounds<<<(NUM_GRAPHS + 1 + B - 1) / B, B, 0, stream>>>(batch, gstart);
  k_gather1<<<((size_t)N_NODES * 4 + B - 1) / B, B, 0, stream>>>(ssrc, offs, xs4, A1);
  k_fin1<<<((size_t)N_NODES * 16 + B - 1) / B, B, 0, stream>>>(A1, xs4, dinv, W1, b1, u);
  k_gather2<<<((size_t)N_NODES * 16 + B - 1) / B, B, 0, stream>>>(ssrc, offs, u, A2);
  k_pool<<<NUM_GRAPHS, B, 0, stream>>>(u, A2, W2, b2, dinv, gstart, sums, cntg);
  k_mlp<<<(NUM_GRAPHS + B - 1) / B, B, 0, stream>>>(sums, cntg, fW1, fb1, fW2, fb2, (float*)d_out);
}

// Round 6
// 529.706 us; speedup vs baseline: 6.4845x; 1.2582x over previous
//
#include <hip/hip_runtime.h>
#include <hip/hip_bf16.h>

constexpr int N_NODES    = 500000;
constexpr int N_EDGES    = 8000000;
constexpr int NUM_GRAPHS = 512;

constexpr int BSHIFT = 12;                              // 4096 nodes / coarse bucket
constexpr int BSIZE  = 1 << BSHIFT;
constexpr int NBKT   = (N_NODES + BSIZE - 1) / BSIZE;   // 123
constexpr int EPB    = 4096;                            // edges per block (pass A)
constexpr int NBLK_A = (N_EDGES + EPB - 1) / EPB;       // 1954
constexpr int NH     = NBKT * NBLK_A;                   // 240342
constexpr int SCAN_B = 256;
constexpr int NSB    = (NH + SCAN_B - 1) / SCAN_B;      // 939

// ---- bf16 helpers (bit-level, RNE pack) ----
__device__ __forceinline__ float bf_lo(unsigned u) { return __uint_as_float(u << 16); }
__device__ __forceinline__ float bf_hi(unsigned u) { return __uint_as_float(u & 0xFFFF0000u); }
__device__ __forceinline__ unsigned short f2bf(float f) {
  unsigned u = __float_as_uint(f);
  return (unsigned short)((u + 0x7FFFu + ((u >> 16) & 1u)) >> 16);
}
__device__ __forceinline__ unsigned packbf(float a, float b) {
  return (unsigned)f2bf(a) | ((unsigned)f2bf(b) << 16);
}

// ---- pass A1: per-block coarse histogram (LDS atomics only) ----
__global__ void k_hist(const int* __restrict__ dst, int* __restrict__ H) {
  __shared__ int h[NBKT];
  for (int i = threadIdx.x; i < NBKT; i += blockDim.x) h[i] = 0;
  __syncthreads();
  int e0 = blockIdx.x * EPB;
  int e1 = min(e0 + EPB, N_EDGES);
  for (int e = e0 + threadIdx.x; e < e1; e += blockDim.x)
    atomicAdd(&h[dst[e] >> BSHIFT], 1);
  __syncthreads();
  for (int i = threadIdx.x; i < NBKT; i += blockDim.x)
    H[i * NBLK_A + blockIdx.x] = h[i];                  // bucket-major
}

// ---- exclusive scan of H (NH ints): 3 kernels ----
__global__ void k_scan1(const int* __restrict__ in, int* __restrict__ out,
                        int* __restrict__ bsum, int n) {
  __shared__ int tmp[SCAN_B];
  int t = threadIdx.x;
  int i = blockIdx.x * SCAN_B + t;
  int v = (i < n) ? in[i] : 0;
  tmp[t] = v;
  __syncthreads();
  for (int off = 1; off < SCAN_B; off <<= 1) {
    int a = (t >= off) ? tmp[t - off] : 0;
    __syncthreads();
    tmp[t] += a;
    __syncthreads();
  }
  if (i < n) out[i] = tmp[t] - v;
  if (t == SCAN_B - 1) bsum[blockIdx.x] = tmp[t];
}

__global__ void k_scan2(int* __restrict__ bsum, int nb) {  // in-place exclusive
  __shared__ int tmp[SCAN_B];
  int t = threadIdx.x;
  int carry = 0;
  for (int base = 0; base < nb; base += SCAN_B) {
    int i = base + t;
    int v = (i < nb) ? bsum[i] : 0;
    tmp[t] = v;
    __syncthreads();
    for (int off = 1; off < SCAN_B; off <<= 1) {
      int a = (t >= off) ? tmp[t - off] : 0;
      __syncthreads();
      tmp[t] += a;
      __syncthreads();
    }
    if (i < nb) bsum[i] = carry + tmp[t] - v;
    carry += tmp[SCAN_B - 1];
    __syncthreads();
  }
}

__global__ void k_scan3(int* __restrict__ out, const int* __restrict__ bsum, int n) {
  int i = blockIdx.x * blockDim.x + threadIdx.x;
  if (i < n) out[i] += bsum[i >> 8];
}

// ---- pass A3: scatter edges into coarse buckets (LDS cursors), packed pairs ----
__global__ void k_scatter_bkt(const int* __restrict__ src, const int* __restrict__ dst,
                              const int* __restrict__ S, int* __restrict__ pairs) {
  __shared__ int cur[NBKT];
  for (int i = threadIdx.x; i < NBKT; i += blockDim.x)
    cur[i] = S[i * NBLK_A + blockIdx.x];
  __syncthreads();
  int e0 = blockIdx.x * EPB;
  int e1 = min(e0 + EPB, N_EDGES);
  for (int e = e0 + threadIdx.x; e < e1; e += blockDim.x) {
    int d = dst[e];
    int pos = atomicAdd(&cur[d >> BSHIFT], 1);
    pairs[pos] = ((d & (BSIZE - 1)) << 19) | src[e];    // src < 2^19
  }
}

// ---- pass B: per-bucket CSR finalize (one block per bucket, 1024 threads) ----
__global__ void __launch_bounds__(1024)
k_csr(const int* __restrict__ pairs, const int* __restrict__ S,
      int* __restrict__ ssrc, int* __restrict__ cnt, int* __restrict__ offs) {
  __shared__ int hist[BSIZE];
  __shared__ int tmp[1024];
  int t = threadIdx.x;
  int bkt = blockIdx.x;
  int n0 = bkt << BSHIFT;
  int e0 = S[bkt * NBLK_A];
  int e1 = (bkt + 1 < NBKT) ? S[(bkt + 1) * NBLK_A] : N_EDGES;
#pragma unroll
  for (int j = 0; j < 4; ++j) hist[t + j * 1024] = 0;
  __syncthreads();
  for (int e = e0 + t; e < e1; e += 1024)
    atomicAdd(&hist[pairs[e] >> 19], 1);
  __syncthreads();
  int c0 = hist[4 * t], c1 = hist[4 * t + 1], c2 = hist[4 * t + 2], c3 = hist[4 * t + 3];
  int tsum = c0 + c1 + c2 + c3;
  tmp[t] = tsum;
  __syncthreads();
  for (int off = 1; off < 1024; off <<= 1) {
    int a = (t >= off) ? tmp[t - off] : 0;
    __syncthreads();
    tmp[t] += a;
    __syncthreads();
  }
  int tbase = tmp[t] - tsum;     // exclusive over threads
  int o0 = tbase, o1 = tbase + c0, o2 = o1 + c1, o3 = o2 + c2;
  hist[4 * t] = o0; hist[4 * t + 1] = o1; hist[4 * t + 2] = o2; hist[4 * t + 3] = o3;
  int oo[4] = {o0, o1, o2, o3};
  int cc[4] = {c0, c1, c2, c3};
#pragma unroll
  for (int j = 0; j < 4; ++j) {
    int n = n0 + 4 * t + j;
    if (n < N_NODES) { cnt[n] = cc[j]; offs[n] = e0 + oo[j]; }
  }
  __syncthreads();
  for (int e = e0 + t; e < e1; e += 1024) {
    int p = pairs[e];
    int r = atomicAdd(&hist[p >> 19], 1);
    ssrc[e0 + r] = p & 0x7FFFF;
  }
  if (bkt == 0 && t == 0) offs[N_NODES] = N_EDGES;
}

// ---- dinv + pre-scaled bf16 features: xsb[n] = {bf(di*x0), bf(di*x1), bf(di*x2), 0} (8B) ----
__global__ void k_prep(const int* __restrict__ cnt, const float* __restrict__ x,
                       float* __restrict__ dinv, unsigned* __restrict__ xsb) {
  int n = blockIdx.x * blockDim.x + threadIdx.x;
  if (n >= N_NODES) return;
  float di = rsqrtf((float)cnt[n] + 1.0f);
  dinv[n] = di;
  const float* xs = x + (size_t)n * 3;
  uint2 v = make_uint2(packbf(di * xs[0], di * xs[1]), packbf(di * xs[2], 0.0f));
  *(uint2*)(xsb + (size_t)n * 2) = v;
}

// ---- graph segment boundaries ----
__global__ void k_bounds(const int* __restrict__ batch, int* __restrict__ start) {
  int g = blockIdx.x * blockDim.x + threadIdx.x;
  if (g > NUM_GRAPHS) return;
  int lo = 0, hi = N_NODES;
  while (lo < hi) { int mid = (lo + hi) >> 1; if (batch[mid] < g) lo = mid + 1; else hi = mid; }
  start[g] = lo;
}

// ---- layer 1 gather: 2 lanes/node, uint (2 bf16) per lane, unroll-2 ----
__global__ void k_gather1(const int* __restrict__ ssrc, const int* __restrict__ offs,
                          const unsigned* __restrict__ xsb, float* __restrict__ A1) {
  unsigned t = blockIdx.x * blockDim.x + threadIdx.x;
  unsigned n = t >> 1;
  int j = t & 1;
  if (n >= (unsigned)N_NODES) return;
  int o0 = offs[n], o1 = offs[n + 1];
  float a0 = 0.0f, a1 = 0.0f;
  int i = o0;
  for (; i + 1 < o1; i += 2) {
    int s0 = ssrc[i], s1 = ssrc[i + 1];
    unsigned q0 = xsb[(size_t)s0 * 2 + j];
    unsigned q1 = xsb[(size_t)s1 * 2 + j];
    a0 += bf_lo(q0) + bf_lo(q1);
    a1 += bf_hi(q0) + bf_hi(q1);
  }
  if (i < o1) {
    unsigned q = xsb[(size_t)ssrc[i] * 2 + j];
    a0 += bf_lo(q); a1 += bf_hi(q);
  }
  *(float2*)&A1[(size_t)n * 4 + 2 * j] = make_float2(a0, a1);
}

// ---- layer 1 finalize: u(bf16) = di * relu( (di*(A1+xs)) @ W1 + b1 ); 8 thr/node, 2 f each ----
__global__ void k_fin1(const float* __restrict__ A1, const unsigned* __restrict__ xsb,
                       const float* __restrict__ dinv, const float* __restrict__ W1,
                       const float* __restrict__ b1, unsigned* __restrict__ ub) {
  unsigned t = blockIdx.x * blockDim.x + threadIdx.x;
  unsigned n = t >> 3;
  int h = t & 7;
  if (n >= (unsigned)N_NODES) return;
  float di = dinv[n];
  float4 a = *(const float4*)&A1[(size_t)n * 4];
  uint2 xq = *(const uint2*)&xsb[(size_t)n * 2];
  float t0 = di * (a.x + bf_lo(xq.x));
  float t1 = di * (a.y + bf_hi(xq.x));
  float t2 = di * (a.z + bf_lo(xq.y));
  int f = 2 * h;
  float v0 = t0 * W1[f]     + t1 * W1[16 + f]     + t2 * W1[32 + f]     + b1[f];
  float v1 = t0 * W1[f + 1] + t1 * W1[16 + f + 1] + t2 * W1[32 + f + 1] + b1[f + 1];
  ub[(size_t)n * 8 + h] = packbf(di * fmaxf(v0, 0.0f), di * fmaxf(v1, 0.0f));
}

// ---- layer 2 gather: 4 lanes/node, uint2 (4 bf16) per lane, unroll-2 ----
__global__ void k_gather2(const int* __restrict__ ssrc, const int* __restrict__ offs,
                          const unsigned* __restrict__ ub, float* __restrict__ A2) {
  unsigned t = blockIdx.x * blockDim.x + threadIdx.x;
  unsigned n = t >> 2;
  int j = t & 3;
  if (n >= (unsigned)N_NODES) return;
  int o0 = offs[n], o1 = offs[n + 1];
  float a0 = 0.0f, a1 = 0.0f, a2 = 0.0f, a3 = 0.0f;
  int i = o0;
  for (; i + 1 < o1; i += 2) {
    int s0 = ssrc[i], s1 = ssrc[i + 1];
    uint2 q0 = *(const uint2*)&ub[(size_t)s0 * 8 + j * 2];
    uint2 q1 = *(const uint2*)&ub[(size_t)s1 * 8 + j * 2];
    a0 += bf_lo(q0.x) + bf_lo(q1.x);
    a1 += bf_hi(q0.x) + bf_hi(q1.x);
    a2 += bf_lo(q0.y) + bf_lo(q1.y);
    a3 += bf_hi(q0.y) + bf_hi(q1.y);
  }
  if (i < o1) {
    uint2 q = *(const uint2*)&ub[(size_t)ssrc[i] * 8 + j * 2];
    a0 += bf_lo(q.x); a1 += bf_hi(q.x); a2 += bf_lo(q.y); a3 += bf_hi(q.y);
  }
  *(float4*)&A2[(size_t)n * 16 + j * 4] = make_float4(a0, a1, a2, a3);
}

// ---- pool: h2 = relu( (di*(A2+u)) @ W2 + b2 ), segment-sum per graph ----
__global__ void k_pool(const unsigned* __restrict__ ub, const float* __restrict__ A2,
                       const float* __restrict__ W2, const float* __restrict__ b2,
                       const float* __restrict__ dinv, const int* __restrict__ start,
                       float* __restrict__ sums, float* __restrict__ cntg) {
  __shared__ float w2s[16 * 32];
  __shared__ float red[8][32];
  for (int i = threadIdx.x; i < 16 * 32; i += blockDim.x) w2s[i] = W2[i];
  __syncthreads();
  int g = blockIdx.x;
  int s0 = start[g], s1 = start[g + 1];
  int f = threadIdx.x & 31, sub = threadIdx.x >> 5;
  float bf = b2[f];
  float acc = 0.0f;
  for (int n = s0 + sub; n < s1; n += 8) {
    float di = dinv[n];
    const float* a2 = A2 + (size_t)n * 16;
    const unsigned* ur = ub + (size_t)n * 8;
    float un[16];
#pragma unroll
    for (int q = 0; q < 8; ++q) {
      unsigned w = ur[q];
      un[2 * q] = bf_lo(w);
      un[2 * q + 1] = bf_hi(w);
    }
    float v = bf;
#pragma unroll
    for (int k = 0; k < 16; ++k) v += di * (a2[k] + un[k]) * w2s[k * 32 + f];
    acc += fmaxf(v, 0.0f);
  }
  red[sub][f] = acc;
  __syncthreads();
  if (threadIdx.x < 32) {
    float tot = 0.0f;
#pragma unroll
    for (int i = 0; i < 8; ++i) tot += red[i][threadIdx.x];
    sums[(size_t)g * 32 + threadIdx.x] = tot;
  }
  if (threadIdx.x == 0) cntg[g] = (float)(s1 - s0);
}

// ---- final MLP + log_softmax ----
__global__ void k_mlp(const float* __restrict__ sums, const float* __restrict__ cntg,
                      const float* __restrict__ fW1, const float* __restrict__ fb1,
                      const float* __restrict__ fW2, const float* __restrict__ fb2,
                      float* __restrict__ out) {
  __shared__ float w1s[32 * 64];
  __shared__ float w2s[64 * 3];
  __shared__ float b1s[64];
  __shared__ float b2s[3];
  for (int i = threadIdx.x; i < 32 * 64; i += blockDim.x) w1s[i] = fW1[i];
  for (int i = threadIdx.x; i < 64 * 3; i += blockDim.x) w2s[i] = fW2[i];
  for (int i = threadIdx.x; i < 64; i += blockDim.x) b1s[i] = fb1[i];
  for (int i = threadIdx.x; i < 3; i += blockDim.x) b2s[i] = fb2[i];
  __syncthreads();
  int g = blockIdx.x * blockDim.x + threadIdx.x;
  if (g >= NUM_GRAPHS) return;
  float c = fmaxf(cntg[g], 1.0f);
  float p[32];
#pragma unroll
  for (int i = 0; i < 32; ++i) p[i] = sums[(size_t)g * 32 + i] / c;
  float z2[3] = {b2s[0], b2s[1], b2s[2]};
  for (int j = 0; j < 64; ++j) {
    float a = b1s[j];
#pragma unroll
    for (int i = 0; i < 32; ++i) a += p[i] * w1s[i * 64 + j];
    a = fmaxf(a, 0.0f);
#pragma unroll
    for (int k = 0; k < 3; ++k) z2[k] += a * w2s[j * 3 + k];
  }
  float m = fmaxf(fmaxf(z2[0], z2[1]), z2[2]);
  float l = logf(expf(z2[0] - m) + expf(z2[1] - m) + expf(z2[2] - m));
#pragma unroll
  for (int k = 0; k < 3; ++k) out[(size_t)g * 3 + k] = z2[k] - m - l;
}

extern "C" void kernel_launch(void* const* d_in, const int* in_sizes, int n_in,
                              void* d_out, int out_size, void* d_ws, size_t ws_size,
                              hipStream_t stream) {
  const float* x     = (const float*)d_in[0];
  const int*   ei    = (const int*)d_in[1];   // [2, E]
  const int*   batch = (const int*)d_in[2];
  const float* W1    = (const float*)d_in[3];
  const float* b1    = (const float*)d_in[4];
  const float* W2    = (const float*)d_in[5];
  const float* b2    = (const float*)d_in[6];
  const float* fW1   = (const float*)d_in[7];
  const float* fb1   = (const float*)d_in[8];
  const float* fW2   = (const float*)d_in[9];
  const float* fb2   = (const float*)d_in[10];
  const int* src = ei;
  const int* dst = ei + N_EDGES;

  // ---- workspace layout (≈99 MB, no memsets needed) ----
  float* ws       = (float*)d_ws;
  float* dinv     = ws;                      // 524,288 f
  unsigned* xsb   = (unsigned*)(dinv + 524288);   // 1,048,576 u32 (500000*2 used)
  unsigned* ub    = xsb + 1048576;           // 4,194,304 u32 (500000*8 used)
  float* A1       = (float*)(ub + 4194304);  // 2,000,000 f
  float* sums     = A1 + 2000000;            // 16384
  float* cntg     = sums + 16384;            // 512
  int* cnt        = (int*)(cntg + 512);      // 524,288
  int* offs       = cnt + 524288;            // 524,288 (N_NODES+1 used)
  int* gstart     = offs + 524288;           // 1024 (513 used)
  int* ssrc       = gstart + 1024;           // 8,000,000
  int* pairs      = ssrc + 8000000;          // 8,000,000
  // aliases (dead ranges reused):
  int* H    = (int*)A1;                      // 262,144 (NH=240342 used)
  int* Sarr = H + 262144;                    // 262,144
  int* bsum = Sarr + 262144;                 // 1024 (NSB=939 used)
  float* A2 = (float*)pairs;                 // pairs dead after k_csr

  const int B = 256;
  k_hist<<<NBLK_A, B, 0, stream>>>(dst, H);
  k_scan1<<<NSB, SCAN_B, 0, stream>>>(H, Sarr, bsum, NH);
  k_scan2<<<1, SCAN_B, 0, stream>>>(bsum, NSB);
  k_scan3<<<(NH + B - 1) / B, B, 0, stream>>>(Sarr, bsum, NH);
  k_scatter_bkt<<<NBLK_A, B, 0, stream>>>(src, dst, Sarr, pairs);
  k_csr<<<NBKT, 1024, 0, stream>>>(pairs, Sarr, ssrc, cnt, offs);
  k_prep<<<(N_NODES + B - 1) / B, B, 0, stream>>>(cnt, x, dinv, xsb);
  k_bounds<<<(NUM_GRAPHS + 1 + B - 1) / B, B, 0, stream>>>(batch, gstart);
  k_gather1<<<((size_t)N_NODES * 2 + B - 1) / B, B, 0, stream>>>(ssrc, offs, xsb, A1);
  k_fin1<<<((size_t)N_NODES * 8 + B - 1) / B, B, 0, stream>>>(A1, xsb, dinv, W1, b1, ub);
  k_gather2<<<((size_t)N_NODES * 4 + B - 1) / B, B, 0, stream>>>(ssrc, offs, ub, A2);
  k_pool<<<NUM_GRAPHS, B, 0, stream>>>(ub, A2, W2, b2, dinv, gstart, sums, cntg);
  k_mlp<<<(NUM_GRAPHS + B - 1) / B, B, 0, stream>>>(sums, cntg, fW1, fb1, fW2, fb2, (float*)d_out);
}